// Round 1
// baseline (278.620 us; speedup 1.0000x reference)
//
#include <hip/hip_runtime.h>
#include <math.h>

#define EMBED 1024
#define HDIM  64
#define BATCH 16
#define SEQ   2048
#define MTOT  (BATCH*SEQ)   // 32768
#define NE    (MTOT*HDIM)   // elements per Q/K/V array

typedef _Float16 f16;
typedef __attribute__((ext_vector_type(8))) _Float16 half8;  // 4 VGPR MFMA A/B frag
typedef __attribute__((ext_vector_type(4))) _Float16 half4;  // 8B LDS store
typedef __attribute__((ext_vector_type(4))) float  float4v;  // MFMA C/D frag

// ---------------------------------------------------------------------------
// Kernel 0: W -> fp16, transposed+concatenated: Wt[192][1024] (tiny)
// ---------------------------------------------------------------------------
__global__ void wprep_kernel(const float* __restrict__ Wq, const float* __restrict__ Wk,
                             const float* __restrict__ Wv, f16* __restrict__ Wt)
{
    int e = blockIdx.x * 256 + threadIdx.x;     // e = gn*1024 + k
    if (e >= 192 * EMBED) return;
    int gn = e >> 10, k = e & 1023;
    int mat = gn >> 6, n = gn & 63;
    const float* W = (mat == 0) ? Wq : ((mat == 1) ? Wk : Wv);
    Wt[e] = (f16)W[k * HDIM + n];
}

// ---------------------------------------------------------------------------
// Kernel 1: fused QKV projection, fp16 MFMA (unchanged this round).
//   grid MTOT/64; block 256 = 4 waves; BM=64, each wave 48 of 192 cols.
// ---------------------------------------------------------------------------
__global__ __launch_bounds__(256)
void qkv_mfma_kernel(const float* __restrict__ X, const f16* __restrict__ Wt,
                     const float* __restrict__ bq, const float* __restrict__ bk, const float* __restrict__ bv,
                     f16* __restrict__ Q, f16* __restrict__ K, f16* __restrict__ Vt)
{
    __shared__ f16 Xs[64 * 72];    // [m][k] pad 64->72 halves
    __shared__ f16 Csv[64 * 72];   // V epilogue transpose [d][m]

    const int tid  = threadIdx.x;
    const int wave = tid >> 6;
    const int lane = tid & 63;
    const int quad = lane >> 4;
    const int c16  = lane & 15;
    const int m0   = blockIdx.x * 64;
    const int gnb  = wave * 3;

    float4v acc[4][3];
    #pragma unroll
    for (int mt = 0; mt < 4; ++mt)
        #pragma unroll
        for (int nt = 0; nt < 3; ++nt)
            acc[mt][nt] = (float4v){0.f, 0.f, 0.f, 0.f};

    // prefetch X tile 0 (64x64 fp32 = 16 KB -> 4 float4/thread)
    float4 pf[4];
    #pragma unroll
    for (int i = 0; i < 4; ++i) {
        int c = tid + 256 * i, m = c >> 4, ko = (c & 15) * 4;
        pf[i] = *(const float4*)(X + (size_t)(m0 + m) * EMBED + ko);
    }

    for (int k0 = 0; k0 < EMBED; k0 += 64) {
        // B-frags for this iter (L2-hot W) — issued before the barrier so the
        // ~200-cyc L2 latency hides under barrier + LDS store
        half8 bh[2][3];
        #pragma unroll
        for (int ks = 0; ks < 2; ++ks)
            #pragma unroll
            for (int nt = 0; nt < 3; ++nt)
                bh[ks][nt] = *(const half8*)(Wt + (size_t)((gnb + nt) * 16 + c16) * EMBED
                                             + k0 + ks * 32 + quad * 8);

        __syncthreads();
        #pragma unroll
        for (int i = 0; i < 4; ++i) {
            int c = tid + 256 * i, m = c >> 4, ko = (c & 15) * 4;
            half4 h = { (f16)pf[i].x, (f16)pf[i].y, (f16)pf[i].z, (f16)pf[i].w };
            *(half4*)&Xs[m * 72 + ko] = h;
        }
        __syncthreads();

        // prefetch next X tile
        {
            int k1 = (k0 + 64) & (EMBED - 1);
            #pragma unroll
            for (int i = 0; i < 4; ++i) {
                int c = tid + 256 * i, m = c >> 4, ko = (c & 15) * 4;
                pf[i] = *(const float4*)(X + (size_t)(m0 + m) * EMBED + k1 + ko);
            }
        }

        #pragma unroll
        for (int ks = 0; ks < 2; ++ks) {
            half8 a[4];
            #pragma unroll
            for (int mt = 0; mt < 4; ++mt)
                a[mt] = *(const half8*)&Xs[(mt * 16 + c16) * 72 + ks * 32 + quad * 8];
            #pragma unroll
            for (int mt = 0; mt < 4; ++mt)
                #pragma unroll
                for (int nt = 0; nt < 3; ++nt)
                    acc[mt][nt] = __builtin_amdgcn_mfma_f32_16x16x32_f16(a[mt], bh[ks][nt], acc[mt][nt], 0, 0, 0);
        }
    }

    // bias (uniform per (wave,nt) 16-col tile lies inside one matrix)
    float bb[3];
    #pragma unroll
    for (int nt = 0; nt < 3; ++nt) {
        int gn = (gnb + nt) * 16 + c16, mat = gn >> 6, cn = gn & 63;
        bb[nt] = ((mat == 0) ? bq : ((mat == 1) ? bk : bv))[cn];
    }

    // Q/K: direct fp16 stores
    #pragma unroll
    for (int mt = 0; mt < 4; ++mt)
        #pragma unroll
        for (int nt = 0; nt < 3; ++nt) {
            int gn = (gnb + nt) * 16 + c16, mat = gn >> 6, cn = gn & 63;
            if (mat < 2) {
                f16* O = mat ? K : Q;
                #pragma unroll
                for (int r = 0; r < 4; ++r)
                    O[(size_t)(m0 + mt * 16 + quad * 4 + r) * HDIM + cn] =
                        (f16)(acc[mt][nt][r] + bb[nt]);
            }
        }

    // V: transpose through LDS, coalesced half8 stores
    __syncthreads();
    #pragma unroll
    for (int mt = 0; mt < 4; ++mt)
        #pragma unroll
        for (int nt = 0; nt < 3; ++nt) {
            int gn = (gnb + nt) * 16 + c16, mat = gn >> 6, cn = gn & 63;
            if (mat == 2) {
                #pragma unroll
                for (int r = 0; r < 4; ++r)
                    Csv[cn * 72 + mt * 16 + quad * 4 + r] = (f16)(acc[mt][nt][r] + bb[nt]);
            }
        }
    __syncthreads();
    {
        int d = tid >> 2, ms = (tid & 3) * 16;
        #pragma unroll
        for (int j = 0; j < 2; ++j)
            *(half8*)(Vt + (size_t)d * MTOT + m0 + ms + 8 * j) =
                *(const half8*)&Csv[d * 72 + ms + 8 * j];
    }
}

// ---------------------------------------------------------------------------
// Kernel 2: flash attention, fp16 MFMA, fixed-shift softmax.
//   RESTRUCTURED: 32 q-rows per wave (two 16-row A-tiles) so each K/V LDS
//   fragment read feeds 2 MFMAs (was 1:1); LDS K/V double-buffered -> ONE
//   barrier per kv-iter (was 2); mask via register + __shfl (no LDS/barrier).
//   grid (SEQ/64, BATCH); block 128 = 2 waves x 32 q-rows; BKV=64.
//   Per wave-iter: 20 ds_read_b128 : 36 MFMA (was 18 : 18).
// ---------------------------------------------------------------------------
__global__ __launch_bounds__(128)
void attn_mfma_kernel(const f16* __restrict__ Q, const f16* __restrict__ K,
                      const f16* __restrict__ Vt, const int* __restrict__ mask,
                      float* __restrict__ out)
{
    __shared__ f16 Ks[2][64 * 72];   // [buf][j][d] pad 64->72
    __shared__ f16 Vs[2][64 * 72];   // [buf][d][j]
    __shared__ f16 Ps[2][32 * 72];   // per-wave P tile (wave-private, no barrier)

    const int tid  = threadIdx.x;
    const int wave = tid >> 6;
    const int lane = tid & 63;
    const int quad = lane >> 4;
    const int c16  = lane & 15;
    const int b    = blockIdx.y;
    const int s0   = blockIdx.x * 64;
    const int q0   = s0 + wave * 32;

    // Q A-frags for both 16-row q-tiles, loaded once
    half8 qa[2][2];
    #pragma unroll
    for (int qt = 0; qt < 2; ++qt) {
        const size_t qrow = (size_t)(b * SEQ + q0 + qt * 16 + c16) * HDIM;
        qa[qt][0] = *(const half8*)(Q + qrow + quad * 8);
        qa[qt][1] = *(const half8*)(Q + qrow + 32 + quad * 8);
    }

    const half8 ones = { (f16)1.f, (f16)1.f, (f16)1.f, (f16)1.f,
                         (f16)1.f, (f16)1.f, (f16)1.f, (f16)1.f };

    float4v O[2][4];
    #pragma unroll
    for (int qt = 0; qt < 2; ++qt)
        #pragma unroll
        for (int dt = 0; dt < 4; ++dt) O[qt][dt] = (float4v){0.f, 0.f, 0.f, 0.f};
    float4v lacc[2];
    lacc[0] = (float4v){0.f, 0.f, 0.f, 0.f};
    lacc[1] = (float4v){0.f, 0.f, 0.f, 0.f};

    const size_t kbase = (size_t)b * SEQ * HDIM;   // K: [MTOT][64]
    const int vcol0 = b * SEQ;                     // Vt: [64][MTOT]

    // prefetch tile 0 (K,V: 8 KB each; 128 threads -> 4 half8 per array)
    half8 pfK[4], pfV[4];
    #pragma unroll
    for (int i = 0; i < 4; ++i) {
        int c = tid + 128 * i, j = c >> 3, o = (c & 7) * 8;
        pfK[i] = *(const half8*)(K  + kbase + (size_t)j * HDIM + o);
        pfV[i] = *(const half8*)(Vt + (size_t)j * MTOT + vcol0 + o);
    }
    int mnext = mask[b * SEQ + lane];

    int cur = 0;
    for (int t0 = 0; t0 < SEQ; t0 += 64) {
        // stage tile t0 into buf[cur] (writes race only with reads of buf[cur^1])
        #pragma unroll
        for (int i = 0; i < 4; ++i) {
            int c = tid + 128 * i, j = c >> 3, o = (c & 7) * 8;
            *(half8*)&Ks[cur][j * 72 + o] = pfK[i];
            *(half8*)&Vs[cur][j * 72 + o] = pfV[i];
        }
        int mcur = mnext;

        // issue next-tile prefetch (wrap on last iter; discarded)
        {
            int t1 = (t0 + 64) & (SEQ - 1);
            #pragma unroll
            for (int i = 0; i < 4; ++i) {
                int c = tid + 128 * i, j = c >> 3, o = (c & 7) * 8;
                pfK[i] = *(const half8*)(K  + kbase + (size_t)(t1 + j) * HDIM + o);
                pfV[i] = *(const half8*)(Vt + (size_t)j * MTOT + vcol0 + t1 + o);
            }
            mnext = mask[b * SEQ + t1 + lane];
        }

        __syncthreads();   // single barrier per iter: stage[cur] now visible

        // mask bits for my 4 column groups (wave-local shuffle, no LDS)
        int mk[4];
        #pragma unroll
        for (int nt = 0; nt < 4; ++nt) mk[nt] = __shfl(mcur, nt * 16 + c16, 64);

        // ---- S = Q K^T : read each K-frag once, feed both q-tiles ----
        float4v s[2][4];
        #pragma unroll
        for (int nt = 0; nt < 4; ++nt) {
            const int krow = (nt * 16 + c16) * 72;
            half8 kh0 = *(const half8*)&Ks[cur][krow + quad * 8];
            half8 kh1 = *(const half8*)&Ks[cur][krow + 32 + quad * 8];
            #pragma unroll
            for (int qt = 0; qt < 2; ++qt) {
                float4v a = (float4v){0.f, 0.f, 0.f, 0.f};
                a = __builtin_amdgcn_mfma_f32_16x16x32_f16(qa[qt][0], kh0, a, 0, 0, 0);
                a = __builtin_amdgcn_mfma_f32_16x16x32_f16(qa[qt][1], kh1, a, 0, 0, 0);
                s[qt][nt] = a;
            }
        }

        // ---- p = exp(s/8 - 6); masked -> exact 0; store fp16 ----
        #pragma unroll
        for (int qt = 0; qt < 2; ++qt)
            #pragma unroll
            for (int nt = 0; nt < 4; ++nt) {
                #pragma unroll
                for (int r = 0; r < 4; ++r) {
                    float t = fmaf(s[qt][nt][r], 0.125f, -6.0f);
                    t = mk[nt] ? t : -1e30f;
                    Ps[wave][(qt * 16 + quad * 4 + r) * 72 + nt * 16 + c16] = (f16)__expf(t);
                }
            }

        // ---- P frags; l via MFMA vs ones; O += P V (V-frags read once) ----
        half8 pa[2][2];
        #pragma unroll
        for (int qt = 0; qt < 2; ++qt) {
            const int prow = (qt * 16 + c16) * 72;
            pa[qt][0] = *(const half8*)&Ps[wave][prow + quad * 8];
            pa[qt][1] = *(const half8*)&Ps[wave][prow + 32 + quad * 8];
        }
        #pragma unroll
        for (int qt = 0; qt < 2; ++qt) {
            lacc[qt] = __builtin_amdgcn_mfma_f32_16x16x32_f16(pa[qt][0], ones, lacc[qt], 0, 0, 0);
            lacc[qt] = __builtin_amdgcn_mfma_f32_16x16x32_f16(pa[qt][1], ones, lacc[qt], 0, 0, 0);
        }
        #pragma unroll
        for (int dt = 0; dt < 4; ++dt) {
            const int vrow = (dt * 16 + c16) * 72;
            half8 vh0 = *(const half8*)&Vs[cur][vrow + quad * 8];
            half8 vh1 = *(const half8*)&Vs[cur][vrow + 32 + quad * 8];
            #pragma unroll
            for (int qt = 0; qt < 2; ++qt) {
                O[qt][dt] = __builtin_amdgcn_mfma_f32_16x16x32_f16(pa[qt][0], vh0, O[qt][dt], 0, 0, 0);
                O[qt][dt] = __builtin_amdgcn_mfma_f32_16x16x32_f16(pa[qt][1], vh1, O[qt][dt], 0, 0, 0);
            }
        }

        cur ^= 1;
    }

    // epilogue: normalize, store fp32
    #pragma unroll
    for (int qt = 0; qt < 2; ++qt)
        #pragma unroll
        for (int r = 0; r < 4; ++r) {
            float inv = 1.0f / lacc[qt][r];
            size_t orow = (size_t)(b * SEQ + q0 + qt * 16 + quad * 4 + r) * HDIM;
            #pragma unroll
            for (int dt = 0; dt < 4; ++dt)
                out[orow + dt * 16 + c16] = O[qt][dt][r] * inv;
        }
}

// ---------------------------------------------------------------------------
extern "C" void kernel_launch(void* const* d_in, const int* in_sizes, int n_in,
                              void* d_out, int out_size, void* d_ws, size_t ws_size,
                              hipStream_t stream) {
    const float* x    = (const float*)d_in[0];
    const int*   mask = (const int*)  d_in[1];
    const float* Wq   = (const float*)d_in[2];
    const float* bq   = (const float*)d_in[3];
    const float* Wk   = (const float*)d_in[4];
    const float* bk   = (const float*)d_in[5];
    const float* Wv   = (const float*)d_in[6];
    const float* bv   = (const float*)d_in[7];
    float* out = (float*)d_out;

    // workspace: Qf, Kf, Vt (fp16, 4 MB each) + Wt (384 KB) = 12.4 MB
    f16* Qf = (f16*)d_ws;
    f16* Kf = Qf + (size_t)NE;
    f16* Vt = Kf + (size_t)NE;
    f16* Wt = Vt + (size_t)NE;

    wprep_kernel<<<dim3(768), dim3(256), 0, stream>>>(Wq, Wk, Wv, Wt);

    qkv_mfma_kernel<<<dim3(MTOT / 64), dim3(256), 0, stream>>>(
        x, Wt, bq, bk, bv, Qf, Kf, Vt);

    attn_mfma_kernel<<<dim3(SEQ / 64, BATCH), dim3(128), 0, stream>>>(
        Qf, Kf, Vt, mask, out);
}

// Round 3
// 263.293 us; speedup vs baseline: 1.0582x; 1.0582x over previous
//
#include <hip/hip_runtime.h>
#include <math.h>

#define EMBED 1024
#define HDIM  64
#define BATCH 16
#define SEQ   2048
#define MTOT  (BATCH*SEQ)   // 32768
#define NE    (MTOT*HDIM)   // elements per Q/K/V array

typedef _Float16 f16;
typedef __attribute__((ext_vector_type(8))) _Float16 half8;  // 4 VGPR MFMA A/B frag
typedef __attribute__((ext_vector_type(4))) _Float16 half4;  // 8B LDS store
typedef __attribute__((ext_vector_type(4))) float  float4v;  // MFMA C/D frag

// ---------------------------------------------------------------------------
// Kernel 0: W -> fp16, transposed+concatenated: Wt[192][1024] (tiny)
// ---------------------------------------------------------------------------
__global__ void wprep_kernel(const float* __restrict__ Wq, const float* __restrict__ Wk,
                             const float* __restrict__ Wv, f16* __restrict__ Wt)
{
    int e = blockIdx.x * 256 + threadIdx.x;     // e = gn*1024 + k
    if (e >= 192 * EMBED) return;
    int gn = e >> 10, k = e & 1023;
    int mat = gn >> 6, n = gn & 63;
    const float* W = (mat == 0) ? Wq : ((mat == 1) ? Wk : Wv);
    Wt[e] = (f16)W[k * HDIM + n];
}

// ---------------------------------------------------------------------------
// Kernel 1: fused QKV projection, fp16 MFMA (unchanged this round).
//   grid MTOT/64; block 256 = 4 waves; BM=64, each wave 48 of 192 cols.
// ---------------------------------------------------------------------------
__global__ __launch_bounds__(256)
void qkv_mfma_kernel(const float* __restrict__ X, const f16* __restrict__ Wt,
                     const float* __restrict__ bq, const float* __restrict__ bk, const float* __restrict__ bv,
                     f16* __restrict__ Q, f16* __restrict__ K, f16* __restrict__ Vt)
{
    __shared__ f16 Xs[64 * 72];    // [m][k] pad 64->72 halves
    __shared__ f16 Csv[64 * 72];   // V epilogue transpose [d][m]

    const int tid  = threadIdx.x;
    const int wave = tid >> 6;
    const int lane = tid & 63;
    const int quad = lane >> 4;
    const int c16  = lane & 15;
    const int m0   = blockIdx.x * 64;
    const int gnb  = wave * 3;

    float4v acc[4][3];
    #pragma unroll
    for (int mt = 0; mt < 4; ++mt)
        #pragma unroll
        for (int nt = 0; nt < 3; ++nt)
            acc[mt][nt] = (float4v){0.f, 0.f, 0.f, 0.f};

    // prefetch X tile 0 (64x64 fp32 = 16 KB -> 4 float4/thread)
    float4 pf[4];
    #pragma unroll
    for (int i = 0; i < 4; ++i) {
        int c = tid + 256 * i, m = c >> 4, ko = (c & 15) * 4;
        pf[i] = *(const float4*)(X + (size_t)(m0 + m) * EMBED + ko);
    }

    for (int k0 = 0; k0 < EMBED; k0 += 64) {
        // B-frags for this iter (L2-hot W) — issued before the barrier so the
        // ~200-cyc L2 latency hides under barrier + LDS store
        half8 bh[2][3];
        #pragma unroll
        for (int ks = 0; ks < 2; ++ks)
            #pragma unroll
            for (int nt = 0; nt < 3; ++nt)
                bh[ks][nt] = *(const half8*)(Wt + (size_t)((gnb + nt) * 16 + c16) * EMBED
                                             + k0 + ks * 32 + quad * 8);

        __syncthreads();
        #pragma unroll
        for (int i = 0; i < 4; ++i) {
            int c = tid + 256 * i, m = c >> 4, ko = (c & 15) * 4;
            half4 h = { (f16)pf[i].x, (f16)pf[i].y, (f16)pf[i].z, (f16)pf[i].w };
            *(half4*)&Xs[m * 72 + ko] = h;
        }
        __syncthreads();

        // prefetch next X tile
        {
            int k1 = (k0 + 64) & (EMBED - 1);
            #pragma unroll
            for (int i = 0; i < 4; ++i) {
                int c = tid + 256 * i, m = c >> 4, ko = (c & 15) * 4;
                pf[i] = *(const float4*)(X + (size_t)(m0 + m) * EMBED + k1 + ko);
            }
        }

        #pragma unroll
        for (int ks = 0; ks < 2; ++ks) {
            half8 a[4];
            #pragma unroll
            for (int mt = 0; mt < 4; ++mt)
                a[mt] = *(const half8*)&Xs[(mt * 16 + c16) * 72 + ks * 32 + quad * 8];
            #pragma unroll
            for (int mt = 0; mt < 4; ++mt)
                #pragma unroll
                for (int nt = 0; nt < 3; ++nt)
                    acc[mt][nt] = __builtin_amdgcn_mfma_f32_16x16x32_f16(a[mt], bh[ks][nt], acc[mt][nt], 0, 0, 0);
        }
    }

    // bias (uniform per (wave,nt) 16-col tile lies inside one matrix)
    float bb[3];
    #pragma unroll
    for (int nt = 0; nt < 3; ++nt) {
        int gn = (gnb + nt) * 16 + c16, mat = gn >> 6, cn = gn & 63;
        bb[nt] = ((mat == 0) ? bq : ((mat == 1) ? bk : bv))[cn];
    }

    // Q/K: direct fp16 stores
    #pragma unroll
    for (int mt = 0; mt < 4; ++mt)
        #pragma unroll
        for (int nt = 0; nt < 3; ++nt) {
            int gn = (gnb + nt) * 16 + c16, mat = gn >> 6, cn = gn & 63;
            if (mat < 2) {
                f16* O = mat ? K : Q;
                #pragma unroll
                for (int r = 0; r < 4; ++r)
                    O[(size_t)(m0 + mt * 16 + quad * 4 + r) * HDIM + cn] =
                        (f16)(acc[mt][nt][r] + bb[nt]);
            }
        }

    // V: transpose through LDS, coalesced half8 stores
    __syncthreads();
    #pragma unroll
    for (int mt = 0; mt < 4; ++mt)
        #pragma unroll
        for (int nt = 0; nt < 3; ++nt) {
            int gn = (gnb + nt) * 16 + c16, mat = gn >> 6, cn = gn & 63;
            if (mat == 2) {
                #pragma unroll
                for (int r = 0; r < 4; ++r)
                    Csv[cn * 72 + mt * 16 + quad * 4 + r] = (f16)(acc[mt][nt][r] + bb[nt]);
            }
        }
    __syncthreads();
    {
        int d = tid >> 2, ms = (tid & 3) * 16;
        #pragma unroll
        for (int j = 0; j < 2; ++j)
            *(half8*)(Vt + (size_t)d * MTOT + m0 + ms + 8 * j) =
                *(const half8*)&Csv[d * 72 + ms + 8 * j];
    }
}

// ---------------------------------------------------------------------------
// Kernel 2: flash attention, fp16 MFMA, fixed-shift softmax.
//   Round 2 (resubmit; round-2 bench was an infra failure, kernel never ran):
//   32 q-rows/wave structure KEPT (2 MFMAs per K/V frag read,
//   36 MFMA : 20 ds_read per wave-iter), occupancy RESTORED:
//   block 256 = 4 waves, BM=128 q-rows/block, grid (SEQ/128, BATCH) = 256
//   blocks -> 1 block/CU = 8 waves/CU = 2 waves/SIMD (same as round-0 best).
//   K/V staging per q-row halved vs round-0. Single barrier per kv-iter
//   (double-buffered LDS); mask via register + __shfl.
// ---------------------------------------------------------------------------
__global__ __launch_bounds__(256)
void attn_mfma_kernel(const f16* __restrict__ Q, const f16* __restrict__ K,
                      const f16* __restrict__ Vt, const int* __restrict__ mask,
                      float* __restrict__ out)
{
    __shared__ f16 Ks[2][64 * 72];   // [buf][j][d] pad 64->72
    __shared__ f16 Vs[2][64 * 72];   // [buf][d][j]
    __shared__ f16 Ps[4][32 * 72];   // per-wave P tile (wave-private, no barrier)

    const int tid  = threadIdx.x;
    const int wave = tid >> 6;
    const int lane = tid & 63;
    const int quad = lane >> 4;
    const int c16  = lane & 15;
    const int b    = blockIdx.y;
    const int s0   = blockIdx.x * 128;
    const int q0   = s0 + wave * 32;

    // Q A-frags for both 16-row q-tiles, loaded once
    half8 qa[2][2];
    #pragma unroll
    for (int qt = 0; qt < 2; ++qt) {
        const size_t qrow = (size_t)(b * SEQ + q0 + qt * 16 + c16) * HDIM;
        qa[qt][0] = *(const half8*)(Q + qrow + quad * 8);
        qa[qt][1] = *(const half8*)(Q + qrow + 32 + quad * 8);
    }

    const half8 ones = { (f16)1.f, (f16)1.f, (f16)1.f, (f16)1.f,
                         (f16)1.f, (f16)1.f, (f16)1.f, (f16)1.f };

    float4v O[2][4];
    #pragma unroll
    for (int qt = 0; qt < 2; ++qt)
        #pragma unroll
        for (int dt = 0; dt < 4; ++dt) O[qt][dt] = (float4v){0.f, 0.f, 0.f, 0.f};
    float4v lacc[2];
    lacc[0] = (float4v){0.f, 0.f, 0.f, 0.f};
    lacc[1] = (float4v){0.f, 0.f, 0.f, 0.f};

    const size_t kbase = (size_t)b * SEQ * HDIM;   // K: [MTOT][64]
    const int vcol0 = b * SEQ;                     // Vt: [64][MTOT]

    // prefetch tile 0 (K,V: 8 KB each; 256 threads -> 2 half8 per array)
    half8 pfK[2], pfV[2];
    #pragma unroll
    for (int i = 0; i < 2; ++i) {
        int c = tid + 256 * i, j = c >> 3, o = (c & 7) * 8;
        pfK[i] = *(const half8*)(K  + kbase + (size_t)j * HDIM + o);
        pfV[i] = *(const half8*)(Vt + (size_t)j * MTOT + vcol0 + o);
    }
    int mnext = mask[b * SEQ + lane];

    int cur = 0;
    for (int t0 = 0; t0 < SEQ; t0 += 64) {
        // stage tile t0 into buf[cur] (writes race only with reads of buf[cur^1])
        #pragma unroll
        for (int i = 0; i < 2; ++i) {
            int c = tid + 256 * i, j = c >> 3, o = (c & 7) * 8;
            *(half8*)&Ks[cur][j * 72 + o] = pfK[i];
            *(half8*)&Vs[cur][j * 72 + o] = pfV[i];
        }
        int mcur = mnext;

        // issue next-tile prefetch (wrap on last iter; discarded)
        {
            int t1 = (t0 + 64) & (SEQ - 1);
            #pragma unroll
            for (int i = 0; i < 2; ++i) {
                int c = tid + 256 * i, j = c >> 3, o = (c & 7) * 8;
                pfK[i] = *(const half8*)(K  + kbase + (size_t)(t1 + j) * HDIM + o);
                pfV[i] = *(const half8*)(Vt + (size_t)j * MTOT + vcol0 + t1 + o);
            }
            mnext = mask[b * SEQ + t1 + lane];
        }

        __syncthreads();   // single barrier per iter: stage[cur] now visible

        // mask bits for my 4 column groups (wave-local shuffle, no LDS)
        int mk[4];
        #pragma unroll
        for (int nt = 0; nt < 4; ++nt) mk[nt] = __shfl(mcur, nt * 16 + c16, 64);

        // ---- S = Q K^T : read each K-frag once, feed both q-tiles ----
        float4v s[2][4];
        #pragma unroll
        for (int nt = 0; nt < 4; ++nt) {
            const int krow = (nt * 16 + c16) * 72;
            half8 kh0 = *(const half8*)&Ks[cur][krow + quad * 8];
            half8 kh1 = *(const half8*)&Ks[cur][krow + 32 + quad * 8];
            #pragma unroll
            for (int qt = 0; qt < 2; ++qt) {
                float4v a = (float4v){0.f, 0.f, 0.f, 0.f};
                a = __builtin_amdgcn_mfma_f32_16x16x32_f16(qa[qt][0], kh0, a, 0, 0, 0);
                a = __builtin_amdgcn_mfma_f32_16x16x32_f16(qa[qt][1], kh1, a, 0, 0, 0);
                s[qt][nt] = a;
            }
        }

        // ---- p = exp(s/8 - 6); masked -> exact 0; store fp16 ----
        #pragma unroll
        for (int qt = 0; qt < 2; ++qt)
            #pragma unroll
            for (int nt = 0; nt < 4; ++nt) {
                #pragma unroll
                for (int r = 0; r < 4; ++r) {
                    float t = fmaf(s[qt][nt][r], 0.125f, -6.0f);
                    t = mk[nt] ? t : -1e30f;
                    Ps[wave][(qt * 16 + quad * 4 + r) * 72 + nt * 16 + c16] = (f16)__expf(t);
                }
            }

        // ---- P frags; l via MFMA vs ones; O += P V (V-frags read once) ----
        half8 pa[2][2];
        #pragma unroll
        for (int qt = 0; qt < 2; ++qt) {
            const int prow = (qt * 16 + c16) * 72;
            pa[qt][0] = *(const half8*)&Ps[wave][prow + quad * 8];
            pa[qt][1] = *(const half8*)&Ps[wave][prow + 32 + quad * 8];
        }
        #pragma unroll
        for (int qt = 0; qt < 2; ++qt) {
            lacc[qt] = __builtin_amdgcn_mfma_f32_16x16x32_f16(pa[qt][0], ones, lacc[qt], 0, 0, 0);
            lacc[qt] = __builtin_amdgcn_mfma_f32_16x16x32_f16(pa[qt][1], ones, lacc[qt], 0, 0, 0);
        }
        #pragma unroll
        for (int dt = 0; dt < 4; ++dt) {
            const int vrow = (dt * 16 + c16) * 72;
            half8 vh0 = *(const half8*)&Vs[cur][vrow + quad * 8];
            half8 vh1 = *(const half8*)&Vs[cur][vrow + 32 + quad * 8];
            #pragma unroll
            for (int qt = 0; qt < 2; ++qt) {
                O[qt][dt] = __builtin_amdgcn_mfma_f32_16x16x32_f16(pa[qt][0], vh0, O[qt][dt], 0, 0, 0);
                O[qt][dt] = __builtin_amdgcn_mfma_f32_16x16x32_f16(pa[qt][1], vh1, O[qt][dt], 0, 0, 0);
            }
        }

        cur ^= 1;
    }

    // epilogue: normalize, store fp32
    #pragma unroll
    for (int qt = 0; qt < 2; ++qt)
        #pragma unroll
        for (int r = 0; r < 4; ++r) {
            float inv = 1.0f / lacc[qt][r];
            size_t orow = (size_t)(b * SEQ + q0 + qt * 16 + quad * 4 + r) * HDIM;
            #pragma unroll
            for (int dt = 0; dt < 4; ++dt)
                out[orow + dt * 16 + c16] = O[qt][dt][r] * inv;
        }
}

// ---------------------------------------------------------------------------
extern "C" void kernel_launch(void* const* d_in, const int* in_sizes, int n_in,
                              void* d_out, int out_size, void* d_ws, size_t ws_size,
                              hipStream_t stream) {
    const float* x    = (const float*)d_in[0];
    const int*   mask = (const int*)  d_in[1];
    const float* Wq   = (const float*)d_in[2];
    const float* bq   = (const float*)d_in[3];
    const float* Wk   = (const float*)d_in[4];
    const float* bk   = (const float*)d_in[5];
    const float* Wv   = (const float*)d_in[6];
    const float* bv   = (const float*)d_in[7];
    float* out = (float*)d_out;

    // workspace: Qf, Kf, Vt (fp16, 4 MB each) + Wt (384 KB) = 12.4 MB
    f16* Qf = (f16*)d_ws;
    f16* Kf = Qf + (size_t)NE;
    f16* Vt = Kf + (size_t)NE;
    f16* Wt = Vt + (size_t)NE;

    wprep_kernel<<<dim3(768), dim3(256), 0, stream>>>(Wq, Wk, Wv, Wt);

    qkv_mfma_kernel<<<dim3(MTOT / 64), dim3(256), 0, stream>>>(
        x, Wt, bq, bk, bv, Qf, Kf, Vt);

    attn_mfma_kernel<<<dim3(SEQ / 128, BATCH), dim3(256), 0, stream>>>(
        Qf, Kf, Vt, mask, out);
}